// Round 1
// baseline (295.906 us; speedup 1.0000x reference)
//
#include <hip/hip_runtime.h>
#include <cstdint>
#include <cstddef>

// HGraphConv: out[b,n,k*128+o] = sum_j softmax_row(mask_k ? E_k : -9e15)[n,j] * (x[b,j,:] @ W[k])[o] + bias
// N=1024, B=64, F_IN=F_OUT=128, 4 hops. Hop 0 mask is identity -> A0 = I -> out0 = x@W0.
//
// ws layout (bf16 bits as unsigned short):
//   Aw  [3][1024][1024]      softmax matrices, hops 1..3        (6 MiB)
//   Htw [3][8192][1024]      Ht[hop][(b*128+o)][j] = (x@Wk)^T   (48 MiB)
//   Wtw [4][128][128]        Wt[k][o][f] = W[k][f][o] in bf16   (128 KiB)

#define NODES 1024
#define BATCH 64
#define FDIM  128

typedef __attribute__((ext_vector_type(8))) short  short8;   // 8 bf16 = 4 VGPRs (MFMA A/B frag)
typedef __attribute__((ext_vector_type(4))) float  floatx4;  // MFMA C/D frag

__device__ __forceinline__ unsigned short f2bf(float f) {
  union { float f; unsigned int u; } v; v.f = f;
  unsigned int r = v.u + 0x7fffu + ((v.u >> 16) & 1u);   // round-to-nearest-even
  return (unsigned short)(r >> 16);
}

__device__ __forceinline__ void async_copy16(const void* g, void* l) {
  // gfx950 global->LDS DMA, 16B per lane; LDS dest = wave-uniform base + lane*16
  __builtin_amdgcn_global_load_lds(
      (const __attribute__((address_space(1))) void*)g,
      (__attribute__((address_space(3))) void*)l, 16, 0, 0);
}

// ---------------------------------------------------------------- kernel 0
__global__ __launch_bounds__(256) void transpose_w(const float* __restrict__ W,
                                                   unsigned short* __restrict__ Wt) {
  const int idx = blockIdx.x * 256 + threadIdx.x;      // 65536 elements
  const int k = idx >> 14, rem = idx & 16383;
  const int f = rem >> 7, o = rem & 127;
  Wt[(k << 14) + o * 128 + f] = f2bf(W[idx]);
}

// ---------------------------------------------------------------- kernel 1
// one block per (row, hop in 1..3): masked softmax over 1024 cols -> bf16 A
__global__ __launch_bounds__(256) void softmax_rows(
    const float* __restrict__ E1, const float* __restrict__ E2, const float* __restrict__ E3,
    const void* __restrict__ m1v, const void* __restrict__ m2v, const void* __restrict__ m3v,
    const void* __restrict__ m0v, unsigned short* __restrict__ Aout) {
  const int row = blockIdx.x, hop = blockIdx.y;
  const int tid = threadIdx.x;
  const int lane = tid & 63, wave = tid >> 6;
  const float* E  = (hop == 0) ? E1 : (hop == 1) ? E2 : E3;
  const void* mv  = (hop == 0) ? m1v : (hop == 1) ? m2v : m3v;
  // layout probe via m0 == identity: int32 layout -> m0[256]==0 (row0,col256 false);
  // byte layout -> bytes 1024..1027 contain the row-1 diagonal (elem 1025) -> nonzero.
  const bool bytelay = (((const int*)m0v)[256] != 0);

  float v[4]; bool mk[4];
#pragma unroll
  for (int i = 0; i < 4; ++i) {
    const int j = tid + i * 256;
    const size_t e = (size_t)row * NODES + j;
    const bool m = bytelay ? (((const unsigned char*)mv)[e] != 0)
                           : (((const int*)mv)[e] != 0);
    mk[i] = m;
    v[i] = m ? E[e] : -__builtin_inff();
  }
  float mx = fmaxf(fmaxf(v[0], v[1]), fmaxf(v[2], v[3]));
#pragma unroll
  for (int off = 32; off > 0; off >>= 1) mx = fmaxf(mx, __shfl_down(mx, off));
  __shared__ float rm[4], rs[4];
  if (lane == 0) rm[wave] = mx;
  __syncthreads();
  mx = fmaxf(fmaxf(rm[0], rm[1]), fmaxf(rm[2], rm[3]));

  float ex[4], s = 0.f;
#pragma unroll
  for (int i = 0; i < 4; ++i) {
    ex[i] = mk[i] ? __expf(v[i] - mx) : 0.f;
    s += ex[i];
  }
#pragma unroll
  for (int off = 32; off > 0; off >>= 1) s += __shfl_down(s, off);
  if (lane == 0) rs[wave] = s;
  __syncthreads();
  s = rs[0] + rs[1] + rs[2] + rs[3];

  const bool uni = (mx == -__builtin_inff());   // fully-masked row -> uniform softmax
  const float inv = uni ? 0.f : 1.f / s;
  unsigned short* dst = Aout + (size_t)hop * NODES * NODES + (size_t)row * NODES;
#pragma unroll
  for (int i = 0; i < 4; ++i) {
    const float val = uni ? (1.f / 1024.f) : ex[i] * inv;
    dst[tid + i * 256] = f2bf(val);
  }
}

// ---------------------------------------------------------------- kernel 2
// per block: one (j-tile of 128, batch b). Stage x tile once (fp32->bf16), then
// loop k=0..3: stage Wt_k, MFMA. k=0: C[j][o] -> out + bias (coalesced).
// k>=1: swapped operands give C[o][j] -> Ht (j-coalesced writes).
__global__ __launch_bounds__(256) void h_gemm(
    const float* __restrict__ x, const unsigned short* __restrict__ Wt,
    const float* __restrict__ bias, unsigned short* __restrict__ Ht,
    float* __restrict__ out) {
  __shared__ unsigned short sX[128 * 128];   // [j][f] bf16, 32 KB
  __shared__ unsigned short sW[128 * 128];   // [o][f] bf16, 32 KB
  const int jt = blockIdx.x, b = blockIdx.y;
  const int tid = threadIdx.x, lane = tid & 63, wave = tid >> 6;
  const int ln = lane & 15, q = lane >> 4;
  const int j0 = jt * 128;

#pragma unroll
  for (int t = 0; t < 16; ++t) {             // stage x tile: 128x128 fp32 -> bf16
    const int g = tid + t * 256;
    const int row = g >> 5, c4 = (g & 31) * 4;
    const float4 vv = *(const float4*)(x + ((size_t)b * NODES + j0 + row) * FDIM + c4);
    ushort4 u;
    u.x = f2bf(vv.x); u.y = f2bf(vv.y); u.z = f2bf(vv.z); u.w = f2bf(vv.w);
    *(ushort4*)(&sX[row * 128 + c4]) = u;
  }

  for (int kz = 0; kz < 4; ++kz) {
#pragma unroll
    for (int t = 0; t < 8; ++t) {            // stage Wt_k via global_load_lds x16
      const int gi = wave * 512 + t * 64 + lane;
      const int row = gi >> 4, c8 = (gi & 15) * 8;
      async_copy16(Wt + (kz << 14) + row * 128 + c8,
                   (char*)sW + (size_t)(wave * 512 + t * 64) * 16);
    }
    __syncthreads();

    const unsigned short* aT = (kz == 0) ? sX : sW;   // A-operand rows (M)
    const unsigned short* bT = (kz == 0) ? sW : sX;   // B-operand cols (N)
    floatx4 acc[2][8];
#pragma unroll
    for (int r = 0; r < 2; ++r)
#pragma unroll
      for (int c = 0; c < 8; ++c) acc[r][c] = (floatx4){0.f, 0.f, 0.f, 0.f};

#pragma unroll
    for (int f0 = 0; f0 < 128; f0 += 32) {
      const int kk = f0 + q * 8;
      short8 af[2], bfr[8];
#pragma unroll
      for (int r = 0; r < 2; ++r)
        af[r] = *(const short8*)(aT + (wave * 32 + r * 16 + ln) * 128 + kk);
#pragma unroll
      for (int c = 0; c < 8; ++c)
        bfr[c] = *(const short8*)(bT + (c * 16 + ln) * 128 + kk);
#pragma unroll
      for (int r = 0; r < 2; ++r)
#pragma unroll
        for (int c = 0; c < 8; ++c)
          acc[r][c] = __builtin_amdgcn_mfma_f32_16x16x32_bf16(af[r], bfr[c], acc[r][c], 0, 0, 0);
    }

    if (kz == 0) {
#pragma unroll
      for (int r = 0; r < 2; ++r)
#pragma unroll
        for (int c = 0; c < 8; ++c) {
          const int o = c * 16 + ln;
          const float bs = bias[o];
#pragma unroll
          for (int reg = 0; reg < 4; ++reg) {
            const int j = j0 + wave * 32 + r * 16 + q * 4 + reg;
            out[((size_t)b * NODES + j) * 512 + o] = acc[r][c][reg] + bs;
          }
        }
    } else {
      unsigned short* H = Ht + (size_t)(kz - 1) * 8192 * 1024;
#pragma unroll
      for (int r = 0; r < 2; ++r)
#pragma unroll
        for (int c = 0; c < 8; ++c)
#pragma unroll
          for (int reg = 0; reg < 4; ++reg) {
            const int o = wave * 32 + r * 16 + q * 4 + reg;
            const int j = j0 + c * 16 + ln;
            H[(size_t)(b * 128 + o) * 1024 + j] = f2bf(acc[r][c][reg]);
          }
    }
    __syncthreads();   // protect sW before next kz staging
  }
}

// ---------------------------------------------------------------- kernel 3
// m97-style 128x128-tile GEMM, BK=64: out[b,i,(hop+1)*128+o] = sum_j A[i,j]*Ht[(b,o),j] + bias
__global__ __launch_bounds__(256) void ah_gemm(
    const unsigned short* __restrict__ Aall, const unsigned short* __restrict__ Htall,
    const float* __restrict__ bias, float* __restrict__ out) {
  __shared__ unsigned short sA[128 * 64];   // [i][j] 16 KB
  __shared__ unsigned short sB[128 * 64];   // [(b,o)][j] 16 KB
  const int bn = blockIdx.x;     // 0..63  == batch (N-tile of 128 == one batch's 128 o's)
  const int bm = blockIdx.y;     // 0..7   i-tile
  const int hop = blockIdx.z;    // 0..2   -> feature block hop+1
  const int tid = threadIdx.x, lane = tid & 63, wave = tid >> 6;
  const int wm = wave >> 1, wn = wave & 1;
  const int ln = lane & 15, q = lane >> 4;
  const int i0 = bm * 128;
  const unsigned short* A = Aall + (size_t)hop * NODES * NODES;
  const unsigned short* H = Htall + (size_t)hop * 8192 * 1024;

  floatx4 acc[4][4];
#pragma unroll
  for (int r = 0; r < 4; ++r)
#pragma unroll
    for (int c = 0; c < 4; ++c) acc[r][c] = (floatx4){0.f, 0.f, 0.f, 0.f};

  for (int kt = 0; kt < 16; ++kt) {
    const int j0 = kt * 64;
#pragma unroll
    for (int t = 0; t < 4; ++t) {            // stage A tile 128x64
      const int gi = wave * 256 + t * 64 + lane;
      const int row = gi >> 3, c8 = (gi & 7) * 8;
      async_copy16(A + (size_t)(i0 + row) * NODES + j0 + c8,
                   (char*)sA + (size_t)(wave * 256 + t * 64) * 16);
    }
#pragma unroll
    for (int t = 0; t < 4; ++t) {            // stage Ht tile 128x64
      const int gi = wave * 256 + t * 64 + lane;
      const int row = gi >> 3, c8 = (gi & 7) * 8;
      async_copy16(H + (size_t)(bn * 128 + row) * NODES + j0 + c8,
                   (char*)sB + (size_t)(wave * 256 + t * 64) * 16);
    }
    __syncthreads();

#pragma unroll
    for (int k0 = 0; k0 < 64; k0 += 32) {
      const int kk = k0 + q * 8;
      short8 af[4], bfr[4];
#pragma unroll
      for (int r = 0; r < 4; ++r)
        af[r] = *(const short8*)(sA + (wm * 64 + r * 16 + ln) * 64 + kk);
#pragma unroll
      for (int c = 0; c < 4; ++c)
        bfr[c] = *(const short8*)(sB + (wn * 64 + c * 16 + ln) * 64 + kk);
#pragma unroll
      for (int r = 0; r < 4; ++r)
#pragma unroll
        for (int c = 0; c < 4; ++c)
          acc[r][c] = __builtin_amdgcn_mfma_f32_16x16x32_bf16(af[r], bfr[c], acc[r][c], 0, 0, 0);
    }
    __syncthreads();
  }

  const int kidx = hop + 1;
#pragma unroll
  for (int r = 0; r < 4; ++r)
#pragma unroll
    for (int c = 0; c < 4; ++c) {
      const int o = wn * 64 + c * 16 + ln;
      const float bs = bias[kidx * 128 + o];
#pragma unroll
      for (int reg = 0; reg < 4; ++reg) {
        const int i = i0 + wm * 64 + r * 16 + q * 4 + reg;
        out[((size_t)bn * NODES + i) * 512 + kidx * 128 + o] = acc[r][c][reg] + bs;
      }
    }
}

// ---------------------------------------------------------------- launcher
extern "C" void kernel_launch(void* const* d_in, const int* in_sizes, int n_in,
                              void* d_out, int out_size, void* d_ws, size_t ws_size,
                              hipStream_t stream) {
  (void)in_sizes; (void)n_in; (void)out_size; (void)ws_size;
  const float* x    = (const float*)d_in[0];
  const float* W    = (const float*)d_in[1];
  const float* E1   = (const float*)d_in[3];
  const float* E2   = (const float*)d_in[4];
  const float* E3   = (const float*)d_in[5];
  const float* bias = (const float*)d_in[6];
  const void*  m0   = d_in[7];
  const void*  m1   = d_in[8];
  const void*  m2   = d_in[9];
  const void*  m3   = d_in[10];
  float* out = (float*)d_out;

  unsigned short* Aw  = (unsigned short*)d_ws;                       // 3 * 1M bf16
  unsigned short* Htw = Aw + (size_t)3 * NODES * NODES;              // 3 * 8M bf16
  unsigned short* Wtw = Htw + (size_t)3 * 8192 * 1024;               // 64K bf16

  transpose_w<<<256, 256, 0, stream>>>(W, Wtw);
  softmax_rows<<<dim3(NODES, 3), 256, 0, stream>>>(E1, E2, E3, m1, m2, m3, m0, Aw);
  h_gemm<<<dim3(8, BATCH), 256, 0, stream>>>(x, Wtw, bias, Htw, out);
  ah_gemm<<<dim3(BATCH, 8, 3), 256, 0, stream>>>(Aw, Htw, bias, out);
}

// Round 2
// 280.299 us; speedup vs baseline: 1.0557x; 1.0557x over previous
//
#include <hip/hip_runtime.h>
#include <cstdint>
#include <cstddef>

// HGraphConv: out[b,n,k*128+o] = sum_j softmax_row(mask_k ? E_k : -9e15)[n,j] * (x[b,j,:] @ W[k])[o] + bias
// N=1024, B=64, F_IN=F_OUT=128, 4 hops. Hop 0 mask is identity -> A0 = I -> out0 = x@W0.
//
// R2: XOR-swizzled LDS layouts in both GEMMs. LDS chunk (row,kb) holds global
// chunk (row, kb^(row&7)); with global_load_lds the swizzle lives in the
// per-lane GLOBAL address (LDS dest must stay linear). Fragment reads XOR the
// chunk index with ln&7 -> ds_read_b128 words spread uniformly 8/bank.
//
// ws layout (bf16 bits as unsigned short):
//   Aw  [3][1024][1024]      softmax matrices, hops 1..3        (6 MiB)
//   Htw [3][8192][1024]      Ht[hop][(b*128+o)][j] = (x@Wk)^T   (48 MiB)
//   Wtw [4][128][128]        Wt[k][o][f] = W[k][f][o] in bf16   (128 KiB)

#define NODES 1024
#define BATCH 64
#define FDIM  128

typedef __attribute__((ext_vector_type(8))) short  short8;   // 8 bf16 = 4 VGPRs (MFMA A/B frag)
typedef __attribute__((ext_vector_type(4))) float  floatx4;  // MFMA C/D frag

__device__ __forceinline__ unsigned short f2bf(float f) {
  union { float f; unsigned int u; } v; v.f = f;
  unsigned int r = v.u + 0x7fffu + ((v.u >> 16) & 1u);   // round-to-nearest-even
  return (unsigned short)(r >> 16);
}

__device__ __forceinline__ void async_copy16(const void* g, void* l) {
  // gfx950 global->LDS DMA, 16B per lane; LDS dest = wave-uniform base + lane*16
  __builtin_amdgcn_global_load_lds(
      (const __attribute__((address_space(1))) void*)g,
      (__attribute__((address_space(3))) void*)l, 16, 0, 0);
}

// ---------------------------------------------------------------- kernel 0
__global__ __launch_bounds__(256) void transpose_w(const float* __restrict__ W,
                                                   unsigned short* __restrict__ Wt) {
  const int idx = blockIdx.x * 256 + threadIdx.x;      // 65536 elements
  const int k = idx >> 14, rem = idx & 16383;
  const int f = rem >> 7, o = rem & 127;
  Wt[(k << 14) + o * 128 + f] = f2bf(W[idx]);
}

// ---------------------------------------------------------------- kernel 1
// one block per (row, hop in 1..3): masked softmax over 1024 cols -> bf16 A
__global__ __launch_bounds__(256) void softmax_rows(
    const float* __restrict__ E1, const float* __restrict__ E2, const float* __restrict__ E3,
    const void* __restrict__ m1v, const void* __restrict__ m2v, const void* __restrict__ m3v,
    const void* __restrict__ m0v, unsigned short* __restrict__ Aout) {
  const int row = blockIdx.x, hop = blockIdx.y;
  const int tid = threadIdx.x;
  const int lane = tid & 63, wave = tid >> 6;
  const float* E  = (hop == 0) ? E1 : (hop == 1) ? E2 : E3;
  const void* mv  = (hop == 0) ? m1v : (hop == 1) ? m2v : m3v;
  // layout probe via m0 == identity: int32 layout -> m0[256]==0 (row0,col256 false);
  // byte layout -> bytes 1024..1027 contain the row-1 diagonal (elem 1025) -> nonzero.
  const bool bytelay = (((const int*)m0v)[256] != 0);

  float v[4]; bool mk[4];
#pragma unroll
  for (int i = 0; i < 4; ++i) {
    const int j = tid + i * 256;
    const size_t e = (size_t)row * NODES + j;
    const bool m = bytelay ? (((const unsigned char*)mv)[e] != 0)
                           : (((const int*)mv)[e] != 0);
    mk[i] = m;
    v[i] = m ? E[e] : -__builtin_inff();
  }
  float mx = fmaxf(fmaxf(v[0], v[1]), fmaxf(v[2], v[3]));
#pragma unroll
  for (int off = 32; off > 0; off >>= 1) mx = fmaxf(mx, __shfl_down(mx, off));
  __shared__ float rm[4], rs[4];
  if (lane == 0) rm[wave] = mx;
  __syncthreads();
  mx = fmaxf(fmaxf(rm[0], rm[1]), fmaxf(rm[2], rm[3]));

  float ex[4], s = 0.f;
#pragma unroll
  for (int i = 0; i < 4; ++i) {
    ex[i] = mk[i] ? __expf(v[i] - mx) : 0.f;
    s += ex[i];
  }
#pragma unroll
  for (int off = 32; off > 0; off >>= 1) s += __shfl_down(s, off);
  if (lane == 0) rs[wave] = s;
  __syncthreads();
  s = rs[0] + rs[1] + rs[2] + rs[3];

  const bool uni = (mx == -__builtin_inff());   // fully-masked row -> uniform softmax
  const float inv = uni ? 0.f : 1.f / s;
  unsigned short* dst = Aout + (size_t)hop * NODES * NODES + (size_t)row * NODES;
#pragma unroll
  for (int i = 0; i < 4; ++i) {
    const float val = uni ? (1.f / 1024.f) : ex[i] * inv;
    dst[tid + i * 256] = f2bf(val);
  }
}

// ---------------------------------------------------------------- kernel 2
// per block: one (j-tile of 128, batch b). Stage x tile once (fp32->bf16), then
// loop k=0..3: stage Wt_k, MFMA. k=0: C[j][o] -> out + bias (coalesced).
// k>=1: swapped operands give C[o][j] -> Ht (j-coalesced writes).
// LDS tiles 128x128 ushort = 16 chunks/row; swizzle XORs low 3 bits of chunk.
__global__ __launch_bounds__(256) void h_gemm(
    const float* __restrict__ x, const unsigned short* __restrict__ Wt,
    const float* __restrict__ bias, unsigned short* __restrict__ Ht,
    float* __restrict__ out) {
  __shared__ unsigned short sX[128 * 128];   // [j][f] bf16, 32 KB (swizzled)
  __shared__ unsigned short sW[128 * 128];   // [o][f] bf16, 32 KB (swizzled)
  const int jt = blockIdx.x, b = blockIdx.y;
  const int tid = threadIdx.x, lane = tid & 63, wave = tid >> 6;
  const int ln = lane & 15, q = lane >> 4;
  const int p = ln & 7;                      // row&7 for all fragment rows (16c+ln)
  const int j0 = jt * 128;

#pragma unroll
  for (int t = 0; t < 16; ++t) {             // stage x tile: 128x128 fp32 -> bf16, swizzled
    const int g = tid + t * 256;
    const int row = g >> 5, c4 = (g & 31) * 4;     // float col 0..124
    const float4 vv = *(const float4*)(x + ((size_t)b * NODES + j0 + row) * FDIM + c4);
    ushort4 u;
    u.x = f2bf(vv.x); u.y = f2bf(vv.y); u.z = f2bf(vv.z); u.w = f2bf(vv.w);
    const int col8 = c4 >> 3, off = c4 & 7;        // chunk 0..15, off in {0,4}
    const int p8 = (col8 & 8) | ((col8 ^ (row & 7)) & 7);
    *(ushort4*)(&sX[row * 128 + p8 * 8 + off]) = u;
  }

  for (int kz = 0; kz < 4; ++kz) {
#pragma unroll
    for (int t = 0; t < 8; ++t) {            // stage Wt_k via global_load_lds x16, swizzled source
      const int gi = wave * 512 + t * 64 + lane;
      const int row = gi >> 4, kb = gi & 15;
      const int src8 = ((kb & 8) | ((kb ^ (row & 7)) & 7)) * 8;
      async_copy16(Wt + (kz << 14) + row * 128 + src8,
                   (char*)sW + (size_t)(wave * 512 + t * 64) * 16);
    }
    __syncthreads();

    const unsigned short* aT = (kz == 0) ? sX : sW;   // A-operand rows (M)
    const unsigned short* bT = (kz == 0) ? sW : sX;   // B-operand cols (N)
    floatx4 acc[2][8];
#pragma unroll
    for (int r = 0; r < 2; ++r)
#pragma unroll
      for (int c = 0; c < 8; ++c) acc[r][c] = (floatx4){0.f, 0.f, 0.f, 0.f};

#pragma unroll
    for (int f0 = 0; f0 < 128; f0 += 32) {
      const int cl = (f0 >> 3) + q;                  // logical chunk 0..15
      const int cp = (cl & 8) | ((cl ^ p) & 7);      // swizzled chunk
      short8 af[2], bfr[8];
#pragma unroll
      for (int r = 0; r < 2; ++r)
        af[r] = *(const short8*)(aT + (wave * 32 + r * 16 + ln) * 128 + cp * 8);
#pragma unroll
      for (int c = 0; c < 8; ++c)
        bfr[c] = *(const short8*)(bT + (c * 16 + ln) * 128 + cp * 8);
#pragma unroll
      for (int r = 0; r < 2; ++r)
#pragma unroll
        for (int c = 0; c < 8; ++c)
          acc[r][c] = __builtin_amdgcn_mfma_f32_16x16x32_bf16(af[r], bfr[c], acc[r][c], 0, 0, 0);
    }

    if (kz == 0) {
#pragma unroll
      for (int r = 0; r < 2; ++r)
#pragma unroll
        for (int c = 0; c < 8; ++c) {
          const int o = c * 16 + ln;
          const float bs = bias[o];
#pragma unroll
          for (int reg = 0; reg < 4; ++reg) {
            const int j = j0 + wave * 32 + r * 16 + q * 4 + reg;
            out[((size_t)b * NODES + j) * 512 + o] = acc[r][c][reg] + bs;
          }
        }
    } else {
      unsigned short* H = Ht + (size_t)(kz - 1) * 8192 * 1024;
#pragma unroll
      for (int r = 0; r < 2; ++r)
#pragma unroll
        for (int c = 0; c < 8; ++c)
#pragma unroll
          for (int reg = 0; reg < 4; ++reg) {
            const int o = wave * 32 + r * 16 + q * 4 + reg;
            const int j = j0 + c * 16 + ln;
            H[(size_t)(b * 128 + o) * 1024 + j] = f2bf(acc[r][c][reg]);
          }
    }
    __syncthreads();   // protect sW before next kz staging
  }
}

// ---------------------------------------------------------------- kernel 3
// m97-style 128x128-tile GEMM, BK=64: out[b,i,(hop+1)*128+o] = sum_j A[i,j]*Ht[(b,o),j] + bias
// LDS tiles 128x64 ushort = 8 chunks/row; swizzle XORs chunk with row&7.
__global__ __launch_bounds__(256) void ah_gemm(
    const unsigned short* __restrict__ Aall, const unsigned short* __restrict__ Htall,
    const float* __restrict__ bias, float* __restrict__ out) {
  __shared__ unsigned short sA[128 * 64];   // [i][j] 16 KB (swizzled)
  __shared__ unsigned short sB[128 * 64];   // [(b,o)][j] 16 KB (swizzled)
  const int bn = blockIdx.x;     // 0..63  == batch (N-tile of 128 == one batch's 128 o's)
  const int bm = blockIdx.y;     // 0..7   i-tile
  const int hop = blockIdx.z;    // 0..2   -> feature block hop+1
  const int tid = threadIdx.x, lane = tid & 63, wave = tid >> 6;
  const int wm = wave >> 1, wn = wave & 1;
  const int ln = lane & 15, q = lane >> 4;
  const int p = ln & 7;          // row&7 for all fragment rows (16c+ln)
  const int i0 = bm * 128;
  const unsigned short* A = Aall + (size_t)hop * NODES * NODES;
  const unsigned short* H = Htall + (size_t)hop * 8192 * 1024;

  floatx4 acc[4][4];
#pragma unroll
  for (int r = 0; r < 4; ++r)
#pragma unroll
    for (int c = 0; c < 4; ++c) acc[r][c] = (floatx4){0.f, 0.f, 0.f, 0.f};

  for (int kt = 0; kt < 16; ++kt) {
    const int j0 = kt * 64;
#pragma unroll
    for (int t = 0; t < 4; ++t) {            // stage A tile 128x64, swizzled source
      const int gi = wave * 256 + t * 64 + lane;
      const int row = gi >> 3, kb = gi & 7;
      const int src8 = (kb ^ (row & 7)) * 8;
      async_copy16(A + (size_t)(i0 + row) * NODES + j0 + src8,
                   (char*)sA + (size_t)(wave * 256 + t * 64) * 16);
    }
#pragma unroll
    for (int t = 0; t < 4; ++t) {            // stage Ht tile 128x64, swizzled source
      const int gi = wave * 256 + t * 64 + lane;
      const int row = gi >> 3, kb = gi & 7;
      const int src8 = (kb ^ (row & 7)) * 8;
      async_copy16(H + (size_t)(bn * 128 + row) * NODES + j0 + src8,
                   (char*)sB + (size_t)(wave * 256 + t * 64) * 16);
    }
    __syncthreads();

#pragma unroll
    for (int k0 = 0; k0 < 64; k0 += 32) {
      const int cl = (k0 >> 3) + q;          // logical chunk 0..7
      const int cp = cl ^ p;                 // swizzled chunk
      short8 af[4], bfr[4];
#pragma unroll
      for (int r = 0; r < 4; ++r)
        af[r] = *(const short8*)(sA + (wm * 64 + r * 16 + ln) * 64 + cp * 8);
#pragma unroll
      for (int c = 0; c < 4; ++c)
        bfr[c] = *(const short8*)(sB + (wn * 64 + c * 16 + ln) * 64 + cp * 8);
#pragma unroll
      for (int r = 0; r < 4; ++r)
#pragma unroll
        for (int c = 0; c < 4; ++c)
          acc[r][c] = __builtin_amdgcn_mfma_f32_16x16x32_bf16(af[r], bfr[c], acc[r][c], 0, 0, 0);
    }
    __syncthreads();
  }

  const int kidx = hop + 1;
#pragma unroll
  for (int r = 0; r < 4; ++r)
#pragma unroll
    for (int c = 0; c < 4; ++c) {
      const int o = wn * 64 + c * 16 + ln;
      const float bs = bias[kidx * 128 + o];
#pragma unroll
      for (int reg = 0; reg < 4; ++reg) {
        const int i = i0 + wm * 64 + r * 16 + q * 4 + reg;
        out[((size_t)bn * NODES + i) * 512 + kidx * 128 + o] = acc[r][c][reg] + bs;
      }
    }
}

// ---------------------------------------------------------------- launcher
extern "C" void kernel_launch(void* const* d_in, const int* in_sizes, int n_in,
                              void* d_out, int out_size, void* d_ws, size_t ws_size,
                              hipStream_t stream) {
  (void)in_sizes; (void)n_in; (void)out_size; (void)ws_size;
  const float* x    = (const float*)d_in[0];
  const float* W    = (const float*)d_in[1];
  const float* E1   = (const float*)d_in[3];
  const float* E2   = (const float*)d_in[4];
  const float* E3   = (const float*)d_in[5];
  const float* bias = (const float*)d_in[6];
  const void*  m0   = d_in[7];
  const void*  m1   = d_in[8];
  const void*  m2   = d_in[9];
  const void*  m3   = d_in[10];
  float* out = (float*)d_out;

  unsigned short* Aw  = (unsigned short*)d_ws;                       // 3 * 1M bf16
  unsigned short* Htw = Aw + (size_t)3 * NODES * NODES;              // 3 * 8M bf16
  unsigned short* Wtw = Htw + (size_t)3 * 8192 * 1024;               // 64K bf16

  transpose_w<<<256, 256, 0, stream>>>(W, Wtw);
  softmax_rows<<<dim3(NODES, 3), 256, 0, stream>>>(E1, E2, E3, m1, m2, m3, m0, Aw);
  h_gemm<<<dim3(8, BATCH), 256, 0, stream>>>(x, Wtw, bias, Htw, out);
  ah_gemm<<<dim3(BATCH, 8, 3), 256, 0, stream>>>(Aw, Htw, bias, out);
}

// Round 3
// 255.377 us; speedup vs baseline: 1.1587x; 1.0976x over previous
//
#include <hip/hip_runtime.h>
#include <cstdint>
#include <cstddef>

// HGraphConv: out[b,n,k*128+o] = sum_j softmax_row(mask_k ? E_k : -9e15)[n,j] * (x[b,j,:] @ W[k])[o] + bias
// N=1024, B=64, F_IN=F_OUT=128, 4 hops. Hop 0 mask is identity -> A0 = I -> out0 = x@W0.
//
// R3: ah_gemm switched to mfma_f32_32x32x16_bf16 (half the MFMA instrs per
// FLOP, higher-ceiling pipe, 128B-coalesced epilogue). Nontemporal stores on
// fp32 out. transpose_w folded into the softmax launch.
//
// ws layout (bf16 bits as unsigned short):
//   Aw  [3][1024][1024]      softmax matrices, hops 1..3        (6 MiB)
//   Htw [3][8192][1024]      Ht[hop][(b*128+o)][j] = (x@Wk)^T   (48 MiB)
//   Wtw [4][128][128]        Wt[k][o][f] = W[k][f][o] in bf16   (128 KiB)

#define NODES 1024
#define BATCH 64
#define FDIM  128

typedef __attribute__((ext_vector_type(8)))  short  short8;    // 8 bf16 = 4 VGPRs (MFMA A/B frag)
typedef __attribute__((ext_vector_type(4)))  float  floatx4;   // 16x16 C/D frag
typedef __attribute__((ext_vector_type(16))) float  floatx16;  // 32x32 C/D frag

__device__ __forceinline__ unsigned short f2bf(float f) {
  union { float f; unsigned int u; } v; v.f = f;
  unsigned int r = v.u + 0x7fffu + ((v.u >> 16) & 1u);   // round-to-nearest-even
  return (unsigned short)(r >> 16);
}

__device__ __forceinline__ void async_copy16(const void* g, void* l) {
  // gfx950 global->LDS DMA, 16B per lane; LDS dest = wave-uniform base + lane*16
  __builtin_amdgcn_global_load_lds(
      (const __attribute__((address_space(1))) void*)g,
      (__attribute__((address_space(3))) void*)l, 16, 0, 0);
}

// ---------------------------------------------------------------- kernel 1
// grid (1024, 4): y<3 -> masked softmax row for hop y+1; y==3 -> W transpose.
__global__ __launch_bounds__(256) void prep(
    const float* __restrict__ E1, const float* __restrict__ E2, const float* __restrict__ E3,
    const void* __restrict__ m1v, const void* __restrict__ m2v, const void* __restrict__ m3v,
    const void* __restrict__ m0v, unsigned short* __restrict__ Aout,
    const float* __restrict__ W, unsigned short* __restrict__ Wt) {
  const int row = blockIdx.x, hop = blockIdx.y;
  const int tid = threadIdx.x;

  if (hop == 3) {                            // W transpose: 256 blocks needed
    if (row < 256) {
      const int idx = row * 256 + tid;       // 65536 elements
      const int k = idx >> 14, rem = idx & 16383;
      const int f = rem >> 7, o = rem & 127;
      Wt[(k << 14) + o * 128 + f] = f2bf(W[idx]);
    }
    return;
  }

  const int lane = tid & 63, wave = tid >> 6;
  const float* E  = (hop == 0) ? E1 : (hop == 1) ? E2 : E3;
  const void* mv  = (hop == 0) ? m1v : (hop == 1) ? m2v : m3v;
  // layout probe via m0 == identity: int32 layout -> m0[256]==0 (row0,col256 false);
  // byte layout -> bytes 1024..1027 contain the row-1 diagonal (elem 1025) -> nonzero.
  const bool bytelay = (((const int*)m0v)[256] != 0);

  float v[4]; bool mk[4];
#pragma unroll
  for (int i = 0; i < 4; ++i) {
    const int j = tid + i * 256;
    const size_t e = (size_t)row * NODES + j;
    const bool m = bytelay ? (((const unsigned char*)mv)[e] != 0)
                           : (((const int*)mv)[e] != 0);
    mk[i] = m;
    v[i] = m ? E[e] : -__builtin_inff();
  }
  float mx = fmaxf(fmaxf(v[0], v[1]), fmaxf(v[2], v[3]));
#pragma unroll
  for (int off = 32; off > 0; off >>= 1) mx = fmaxf(mx, __shfl_down(mx, off));
  __shared__ float rm[4], rs[4];
  if (lane == 0) rm[wave] = mx;
  __syncthreads();
  mx = fmaxf(fmaxf(rm[0], rm[1]), fmaxf(rm[2], rm[3]));

  float ex[4], s = 0.f;
#pragma unroll
  for (int i = 0; i < 4; ++i) {
    ex[i] = mk[i] ? __expf(v[i] - mx) : 0.f;
    s += ex[i];
  }
#pragma unroll
  for (int off = 32; off > 0; off >>= 1) s += __shfl_down(s, off);
  if (lane == 0) rs[wave] = s;
  __syncthreads();
  s = rs[0] + rs[1] + rs[2] + rs[3];

  const bool uni = (mx == -__builtin_inff());   // fully-masked row -> uniform softmax
  const float inv = uni ? 0.f : 1.f / s;
  unsigned short* dst = Aout + (size_t)hop * NODES * NODES + (size_t)row * NODES;
#pragma unroll
  for (int i = 0; i < 4; ++i) {
    const float val = uni ? (1.f / 1024.f) : ex[i] * inv;
    dst[tid + i * 256] = f2bf(val);
  }
}

// ---------------------------------------------------------------- kernel 2
// per block: one (j-tile of 128, batch b). Stage x tile once (fp32->bf16), then
// loop k=0..3: stage Wt_k, MFMA. k=0: C[j][o] -> out + bias (coalesced, nt).
// k>=1: swapped operands give C[o][j] -> Ht (j-coalesced writes).
// LDS tiles 128x128 ushort = 16 chunks/row; swizzle XORs low 3 bits of chunk.
__global__ __launch_bounds__(256) void h_gemm(
    const float* __restrict__ x, const unsigned short* __restrict__ Wt,
    const float* __restrict__ bias, unsigned short* __restrict__ Ht,
    float* __restrict__ out) {
  __shared__ unsigned short sX[128 * 128];   // [j][f] bf16, 32 KB (swizzled)
  __shared__ unsigned short sW[128 * 128];   // [o][f] bf16, 32 KB (swizzled)
  const int jt = blockIdx.x, b = blockIdx.y;
  const int tid = threadIdx.x, lane = tid & 63, wave = tid >> 6;
  const int ln = lane & 15, q = lane >> 4;
  const int p = ln & 7;                      // row&7 for all fragment rows (16c+ln)
  const int j0 = jt * 128;

#pragma unroll
  for (int t = 0; t < 16; ++t) {             // stage x tile: 128x128 fp32 -> bf16, swizzled
    const int g = tid + t * 256;
    const int row = g >> 5, c4 = (g & 31) * 4;     // float col 0..124
    const float4 vv = *(const float4*)(x + ((size_t)b * NODES + j0 + row) * FDIM + c4);
    ushort4 u;
    u.x = f2bf(vv.x); u.y = f2bf(vv.y); u.z = f2bf(vv.z); u.w = f2bf(vv.w);
    const int col8 = c4 >> 3, off = c4 & 7;        // chunk 0..15, off in {0,4}
    const int p8 = (col8 & 8) | ((col8 ^ (row & 7)) & 7);
    *(ushort4*)(&sX[row * 128 + p8 * 8 + off]) = u;
  }

  for (int kz = 0; kz < 4; ++kz) {
#pragma unroll
    for (int t = 0; t < 8; ++t) {            // stage Wt_k via global_load_lds x16, swizzled source
      const int gi = wave * 512 + t * 64 + lane;
      const int row = gi >> 4, kb = gi & 15;
      const int src8 = ((kb & 8) | ((kb ^ (row & 7)) & 7)) * 8;
      async_copy16(Wt + (kz << 14) + row * 128 + src8,
                   (char*)sW + (size_t)(wave * 512 + t * 64) * 16);
    }
    __syncthreads();

    const unsigned short* aT = (kz == 0) ? sX : sW;   // A-operand rows (M)
    const unsigned short* bT = (kz == 0) ? sW : sX;   // B-operand cols (N)
    floatx4 acc[2][8];
#pragma unroll
    for (int r = 0; r < 2; ++r)
#pragma unroll
      for (int c = 0; c < 8; ++c) acc[r][c] = (floatx4){0.f, 0.f, 0.f, 0.f};

#pragma unroll
    for (int f0 = 0; f0 < 128; f0 += 32) {
      const int cl = (f0 >> 3) + q;                  // logical chunk 0..15
      const int cp = (cl & 8) | ((cl ^ p) & 7);      // swizzled chunk
      short8 af[2], bfr[8];
#pragma unroll
      for (int r = 0; r < 2; ++r)
        af[r] = *(const short8*)(aT + (wave * 32 + r * 16 + ln) * 128 + cp * 8);
#pragma unroll
      for (int c = 0; c < 8; ++c)
        bfr[c] = *(const short8*)(bT + (c * 16 + ln) * 128 + cp * 8);
#pragma unroll
      for (int r = 0; r < 2; ++r)
#pragma unroll
        for (int c = 0; c < 8; ++c)
          acc[r][c] = __builtin_amdgcn_mfma_f32_16x16x32_bf16(af[r], bfr[c], acc[r][c], 0, 0, 0);
    }

    if (kz == 0) {
#pragma unroll
      for (int r = 0; r < 2; ++r)
#pragma unroll
        for (int c = 0; c < 8; ++c) {
          const int o = c * 16 + ln;
          const float bs = bias[o];
#pragma unroll
          for (int reg = 0; reg < 4; ++reg) {
            const int j = j0 + wave * 32 + r * 16 + q * 4 + reg;
            __builtin_nontemporal_store(acc[r][c][reg] + bs,
                                        out + ((size_t)b * NODES + j) * 512 + o);
          }
        }
    } else {
      unsigned short* H = Ht + (size_t)(kz - 1) * 8192 * 1024;
#pragma unroll
      for (int r = 0; r < 2; ++r)
#pragma unroll
        for (int c = 0; c < 8; ++c)
#pragma unroll
          for (int reg = 0; reg < 4; ++reg) {
            const int o = wave * 32 + r * 16 + q * 4 + reg;
            const int j = j0 + c * 16 + ln;
            H[(size_t)(b * 128 + o) * 1024 + j] = f2bf(acc[r][c][reg]);
          }
    }
    __syncthreads();   // protect sW before next kz staging
  }
}

// ---------------------------------------------------------------- kernel 3
// 128x128-tile GEMM, BK=64, mfma_f32_32x32x16_bf16 (2x2 of 32x32 per wave):
//   out[b,i,(hop+1)*128+o] = sum_j A[i,j]*Ht[(b,o),j] + bias
// LDS tiles 128x64 ushort = 8 chunks/row; swizzle XORs chunk with row&7.
// A-frag: A[m=lane&31][k=(lane>>5)*8+j]; C/D: col=lane&31,
// row=(reg&3)+8*(reg>>2)+4*(lane>>5)  [measured m74/m101].
__global__ __launch_bounds__(256) void ah_gemm(
    const unsigned short* __restrict__ Aall, const unsigned short* __restrict__ Htall,
    const float* __restrict__ bias, float* __restrict__ out) {
  __shared__ unsigned short sA[128 * 64];   // [i][j] 16 KB (swizzled)
  __shared__ unsigned short sB[128 * 64];   // [(b,o)][j] 16 KB (swizzled)
  const int bn = blockIdx.x;     // 0..63  == batch (N-tile of 128 == one batch's 128 o's)
  const int bm = blockIdx.y;     // 0..7   i-tile
  const int hop = blockIdx.z;    // 0..2   -> feature block hop+1
  const int tid = threadIdx.x, lane = tid & 63, wave = tid >> 6;
  const int wm = wave >> 1, wn = wave & 1;
  const int l32 = lane & 31, h32 = lane >> 5;
  const int p = l32 & 7;         // row&7 for all fragment rows (32c + l32)
  const int i0 = bm * 128;
  const unsigned short* A = Aall + (size_t)hop * NODES * NODES;
  const unsigned short* H = Htall + (size_t)hop * 8192 * 1024;

  floatx16 acc[2][2];
#pragma unroll
  for (int r = 0; r < 2; ++r)
#pragma unroll
    for (int c = 0; c < 2; ++c)
#pragma unroll
      for (int e = 0; e < 16; ++e) acc[r][c][e] = 0.f;

  for (int kt = 0; kt < 16; ++kt) {
    const int j0 = kt * 64;
#pragma unroll
    for (int t = 0; t < 4; ++t) {            // stage A tile 128x64, swizzled source
      const int gi = wave * 256 + t * 64 + lane;
      const int row = gi >> 3, kb = gi & 7;
      const int src8 = (kb ^ (row & 7)) * 8;
      async_copy16(A + (size_t)(i0 + row) * NODES + j0 + src8,
                   (char*)sA + (size_t)(wave * 256 + t * 64) * 16);
    }
#pragma unroll
    for (int t = 0; t < 4; ++t) {            // stage Ht tile 128x64, swizzled source
      const int gi = wave * 256 + t * 64 + lane;
      const int row = gi >> 3, kb = gi & 7;
      const int src8 = (kb ^ (row & 7)) * 8;
      async_copy16(H + (size_t)(bn * 128 + row) * NODES + j0 + src8,
                   (char*)sB + (size_t)(wave * 256 + t * 64) * 16);
    }
    __syncthreads();

#pragma unroll
    for (int k0 = 0; k0 < 64; k0 += 16) {    // 4 k-steps of 16
      const int cl = (k0 >> 3) + h32;        // logical chunk 0..7
      const int cp = cl ^ p;                 // swizzled chunk
      short8 af[2], bfr[2];
#pragma unroll
      for (int r = 0; r < 2; ++r)
        af[r] = *(const short8*)(sA + (wm * 64 + r * 32 + l32) * 64 + cp * 8);
#pragma unroll
      for (int c = 0; c < 2; ++c)
        bfr[c] = *(const short8*)(sB + (wn * 64 + c * 32 + l32) * 64 + cp * 8);
#pragma unroll
      for (int r = 0; r < 2; ++r)
#pragma unroll
        for (int c = 0; c < 2; ++c)
          acc[r][c] = __builtin_amdgcn_mfma_f32_32x32x16_bf16(af[r], bfr[c], acc[r][c], 0, 0, 0);
    }
    __syncthreads();
  }

  const int kidx = hop + 1;
#pragma unroll
  for (int r = 0; r < 2; ++r)
#pragma unroll
    for (int c = 0; c < 2; ++c) {
      const int o = wn * 64 + c * 32 + l32;
      const float bs = bias[kidx * 128 + o];
#pragma unroll
      for (int reg = 0; reg < 16; ++reg) {
        const int rowin = (reg & 3) + 8 * (reg >> 2) + 4 * h32;
        const int i = i0 + wm * 64 + r * 32 + rowin;
        __builtin_nontemporal_store(acc[r][c][reg] + bs,
                                    out + ((size_t)bn * NODES + i) * 512 + kidx * 128 + o);
      }
    }
}

// ---------------------------------------------------------------- launcher
extern "C" void kernel_launch(void* const* d_in, const int* in_sizes, int n_in,
                              void* d_out, int out_size, void* d_ws, size_t ws_size,
                              hipStream_t stream) {
  (void)in_sizes; (void)n_in; (void)out_size; (void)ws_size;
  const float* x    = (const float*)d_in[0];
  const float* W    = (const float*)d_in[1];
  const float* E1   = (const float*)d_in[3];
  const float* E2   = (const float*)d_in[4];
  const float* E3   = (const float*)d_in[5];
  const float* bias = (const float*)d_in[6];
  const void*  m0   = d_in[7];
  const void*  m1   = d_in[8];
  const void*  m2   = d_in[9];
  const void*  m3   = d_in[10];
  float* out = (float*)d_out;

  unsigned short* Aw  = (unsigned short*)d_ws;                       // 3 * 1M bf16
  unsigned short* Htw = Aw + (size_t)3 * NODES * NODES;              // 3 * 8M bf16
  unsigned short* Wtw = Htw + (size_t)3 * 8192 * 1024;               // 64K bf16

  prep<<<dim3(NODES, 4), 256, 0, stream>>>(E1, E2, E3, m1, m2, m3, m0, Aw, W, Wtw);
  h_gemm<<<dim3(8, BATCH), 256, 0, stream>>>(x, Wtw, bias, Htw, out);
  ah_gemm<<<dim3(BATCH, 8, 3), 256, 0, stream>>>(Aw, Htw, bias, out);
}